// Round 1
// baseline (83.279 us; speedup 1.0000x reference)
//
#include <hip/hip_runtime.h>
#include <math.h>

#define NQ 10
#define NLAYERS 4
#define NGATES (NLAYERS * NQ)

typedef float v2f __attribute__((ext_vector_type(2)));
typedef float v4f __attribute__((ext_vector_type(4)));

__device__ __forceinline__ v2f mk2(float a, float b) { v2f r; r.x = a; r.y = b; return r; }

// m = pack_u(re,im) = {re,re,-im,im} representing u = re + i*im
__device__ __forceinline__ v2f cmul_m(v4f m, v2f s) {            // u*s
    v2f r = m.xy * s;
    return __builtin_elementwise_fma(m.zw, s.yx, r);
}
__device__ __forceinline__ v2f cfma_m(v2f acc, v4f m, v2f s) {   // acc + u*s
    acc = __builtin_elementwise_fma(m.xy, s, acc);
    acc = __builtin_elementwise_fma(m.zw, s.yx, acc);
    return acc;
}
__device__ __forceinline__ v2f cmul_mc(v4f m, v2f s) {           // conj(u)*s
    v2f r = m.xy * s;
    return __builtin_elementwise_fma(-m.zw, s.yx, r);
}
__device__ __forceinline__ v2f cfms_mc(v2f acc, v4f m, v2f s) {  // acc - conj(u)*s
    acc = __builtin_elementwise_fma(-m.xy, s, acc);
    acc = __builtin_elementwise_fma(m.zw, s.yx, acc);
    return acc;
}
__device__ __forceinline__ v2f cmul(v2f a, v2f b) {              // generic complex mul
    v2f r = a.xx * b;
    return __builtin_elementwise_fma(mk2(-a.y, a.y), b.yx, r);
}
__device__ __forceinline__ v4f pack_u(float re, float im) {
    v4f m; m.x = re; m.y = re; m.z = -im; m.w = im; return m;
}

// CNOT-ring permutations on the 10-bit amp index (GF(2)-linear; verified prior session)
__host__ __device__ constexpr int pxor1(int v) {   // off = 1 (even layers)
    int y = v; y ^= y >> 1; y ^= y >> 2; y ^= y >> 4; y ^= y >> 8;
    return (y & 0x1FF) | (((y ^ (v >> 9)) & 1) << 9);
}
__host__ __device__ constexpr int pxor5(int v) {   // off = 5 (odd layers)
    int lo = v & 31, hi = (v >> 5) & 31;
    return (lo << 5) | (lo ^ hi);
}

// SU(2) gate on register bit b; only m0=u00, m1=u01 stored (u10=-conj(u01), u11=conj(u00)
// folded into FMA sign modifiers -- same pk_fma count as the 4-mat form).
__device__ __forceinline__ void apply_gate16(v2f* st, const v4f* __restrict__ M, int b) {
    v4f m0 = M[0], m1 = M[1];
    #pragma unroll
    for (int g = 0; g < 8; ++g) {
        int r0 = ((g >> b) << (b + 1)) | (g & ((1 << b) - 1));
        int r1 = r0 | (1 << b);
        v2f s0 = st[r0], s1 = st[r1];
        st[r0] = cfma_m(cmul_m(m0, s0), m1, s1);          // u00*s0 + u01*s1
        st[r1] = cfms_mc(cmul_mc(m0, s1), m1, s0);        // conj(u00)*s1 - conj(u01)*s0
    }
}

__device__ __forceinline__ v2f shflx2(v2f v, int m) {
    v2f r;
    r.x = __shfl_xor(v.x, m, 64);
    r.y = __shfl_xor(v.y, m, 64);
    return r;
}

// gate on a lane-resident qubit (lane-bit mask m); per-lane sign-adjusted coefficient mats
__device__ __forceinline__ void apply_gate_lane(v2f* st, const v4f* __restrict__ M, int m, int lane) {
    v4f m0 = M[0], m1 = M[1];
    v4f mA = m0, mB = m1;
    if (lane & m) { mA.z = -mA.z; mA.w = -mA.w; mB.x = -mB.x; mB.y = -mB.y; }
    #pragma unroll
    for (int r = 0; r < 16; ++r) {
        v2f mine = st[r];
        v2f th = shflx2(mine, m);
        st[r] = cfma_m(cmul_m(mA, mine), mB, th);
    }
}

// Scratch layout: 64 rows x 16 cols (v2f), slot = row*16 + (col ^ ((row&7)<<1)).
// XOR swizzle keeps b128 reads 16B-aligned and makes both reads and all three
// scatter patterns bank-minimum-rate (write bank map is rank-4 in lane bits).
__device__ __forceinline__ void read_row(v2f* st, const v2f* scratch, int lane) {
    const int e = (lane & 7) << 1;
    const v2f* row = scratch + lane * 16;
    #pragma unroll
    for (int h = 0; h < 8; ++h) {
        v4f t = *(const v4f*)(row + ((2 * h) ^ e));   // cols 2h, 2h+1 (e even)
        st[2 * h]     = t.xy;
        st[2 * h + 1] = t.zw;
    }
}

// Layouts (1 sample/wave, amp idx j[9:0], qubit q = bit 9-q):
//  A: lane = j[9:4], reg rA = j[3:0]  -> qubits 6..9 in regs, q4/q5 on lane bits 1/0
//  B: lane = j[5:0], reg rB = j[9:6]  -> qubits 0..3 in regs
// Layer 0's rotations folded into encoding factors; layer 3's CNOT perm folded into
// measurement signs (GF(2)-linear parities -> Walsh-Hadamard coefficients).
__global__ __launch_bounds__(64, 4) void qsim_kernel(const float* __restrict__ x,
                                                     const float* __restrict__ w,
                                                     float* __restrict__ out)
{
    __shared__ __align__(16) v2f scratch[1024];        // 8 KiB
    __shared__ __align__(16) v4f matsL[NGATES * 2];    // 1.25 KiB (u00,u01 only)
    __shared__ __align__(16) v2f encf[NQ][2];

    const int lane = threadIdx.x;
    const long sample = blockIdx.x;

    // ---- 40 variational gates: store only u00,u01 ----
    if (lane < NGATES) {
        float w0 = w[lane*3+0], w1 = w[lane*3+1], w2 = w[lane*3+2];
        float hs = 0.5f*(w0+w2), hd = 0.5f*(w0-w2), hy = 0.5f*w1;
        float cy, sy, cs, ss, cd, sd;
        sincosf(hy, &sy, &cy);
        sincosf(hs, &ss, &cs);
        sincosf(hd, &sd, &cd);
        matsL[lane*2+0] = pack_u( cy*cs, -cy*ss);   // u00 of RZ(w2)RY(w1)RZ(w0)
        matsL[lane*2+1] = pack_u(-sy*cd, -sy*sd);   // u01
    }
    // ---- encoding factors with layer-0 rotations folded: g_q = U_{0,q} * f_q ----
    if (lane < NQ) {
        const float* xs = x + sample * (2 * NQ);
        float th = 0.7853981633974483f * (xs[lane] + 1.0f);
        float ph = 0.7853981633974483f * (xs[NQ + lane] + 1.0f);
        float cy, sy, cp, sp;
        sincosf(th, &sy, &cy);
        sincosf(ph, &sp, &cp);
        const float inv = 0.7071067811865476f;
        float a = (cy - sy) * inv, b = (cy + sy) * inv;
        v2f f0 = mk2(cp * a, -sp * a);   // column 0 of RZ(phi) RY(theta) H
        v2f f1 = mk2(cp * b,  sp * b);
        v4f M0 = matsL[lane*2+0], M1 = matsL[lane*2+1];  // own-lane RAW through LDS: safe
        encf[lane][0] = cfma_m(cmul_m(M0, f0), M1, f1);
        encf[lane][1] = cfms_mc(cmul_mc(M0, f1), M1, f0);
    }
    __syncthreads();

    // ---- product-state init in layout B (lane bit k = qubit 9-k; rB bit k = qubit 3-k) ----
    v2f st[16];
    {
        v2f L = cmul(encf[4][(lane >> 5) & 1], encf[5][(lane >> 4) & 1]);
        L = cmul(L, encf[6][(lane >> 3) & 1]);
        L = cmul(L, encf[7][(lane >> 2) & 1]);
        L = cmul(L, encf[8][(lane >> 1) & 1]);
        L = cmul(L, encf[9][lane & 1]);
        v2f hi2[4], lo2[4], Lh[4];
        #pragma unroll
        for (int a2 = 0; a2 < 4; ++a2) {
            hi2[a2] = cmul(encf[0][(a2 >> 1) & 1], encf[1][a2 & 1]);
            lo2[a2] = cmul(encf[2][(a2 >> 1) & 1], encf[3][a2 & 1]);
        }
        #pragma unroll
        for (int a2 = 0; a2 < 4; ++a2) Lh[a2] = cmul(L, hi2[a2]);
        #pragma unroll
        for (int r = 0; r < 16; ++r)
            st[r] = cmul(Lh[r >> 2], lo2[r & 3]);
    }

    const int jb1 = pxor1(lane), jb5 = pxor5(lane);   // P(j) = P(r<<6) ^ P(lane)

    // ---- layer 0 = CNOT perm only: scatter B -> A with pxor1 ----
    __syncthreads();
    #pragma unroll
    for (int r = 0; r < 16; ++r) {
        const int jc = pxor1(r << 6);
        const int jp = jc ^ jb1;
        const int row = jp >> 4;
        scratch[(row << 4) + ((jp & 15) ^ ((row & 7) << 1))] = st[r];
    }
    __syncthreads();
    read_row(st, scratch, lane);

    // ---- layers 1..3 ----
    #pragma unroll
    for (int l = 1; l < NLAYERS; ++l) {
        const v4f* Ml = matsL + l * NQ * 2;
        // layout A: qubits 6..9 in regs (bit 9-q), q4/q5 via shfl_xor on lane bits 1/0
        apply_gate16(st, Ml + 6*2, 3);
        apply_gate16(st, Ml + 7*2, 2);
        apply_gate16(st, Ml + 8*2, 1);
        apply_gate16(st, Ml + 9*2, 0);
        apply_gate_lane(st, Ml + 4*2, 2, lane);
        apply_gate_lane(st, Ml + 5*2, 1, lane);

        // transpose A -> B: rowB = ((lane&3)<<4)|r, colB = lane>>2, rowB&7 == r&7
        __syncthreads();
        {
            const int b0 = (lane & 3) << 8;
            const int cc = lane >> 2;
            #pragma unroll
            for (int r = 0; r < 16; ++r)
                scratch[b0 + (r << 4) + (cc ^ ((r & 7) << 1))] = st[r];
        }
        __syncthreads();
        read_row(st, scratch, lane);

        // layout B: qubits 0..3 in regs (bit 3-q)
        apply_gate16(st, Ml + 0*2, 3);
        apply_gate16(st, Ml + 1*2, 2);
        apply_gate16(st, Ml + 2*2, 1);
        apply_gate16(st, Ml + 3*2, 0);

        if (l < NLAYERS - 1) {
            // perm-scatter B -> A with layer-l CNOT ring folded into addresses
            __syncthreads();
            const int jb = (l & 1) ? jb5 : jb1;
            #pragma unroll
            for (int r = 0; r < 16; ++r) {
                const int jc = (l & 1) ? pxor5(r << 6) : pxor1(r << 6);  // compile-time
                const int jp = jc ^ jb;
                const int row = jp >> 4;
                scratch[(row << 4) + ((jp & 15) ^ ((row & 7) << 1))] = st[r];
            }
            __syncthreads();
            read_row(st, scratch, lane);
        }
    }

    // ---- measurement in B with layer-3 perm (pxor5) folded into signs ----
    // j' = P3(j): j'[9:5] = lane[4:0]; j'[4:0] = lane[4:0] ^ ((rB<<1)|lane5)
    //  q0..q4 sign bits: lane4,lane3,lane2,lane1,lane0  (on S)
    //  q5..q8 sign bits: lane4^rB3, lane3^rB2, lane2^rB1, lane1^rB0  (reg trees tb3..tb0)
    //  q9 sign bit:      lane0^lane5                      (on S)
    {
        float p[16];
        #pragma unroll
        for (int r = 0; r < 16; ++r) {
            v2f a = st[r]; v2f q2 = a * a; p[r] = q2.x + q2.y;
        }
        float s0[8], s1[4], s2[2];
        float tb0 = 0.f, tb1 = 0.f, tb2, tb3, S;
        #pragma unroll
        for (int k = 0; k < 8; ++k) { s0[k] = p[2*k] + p[2*k+1]; tb0 += p[2*k] - p[2*k+1]; }
        #pragma unroll
        for (int k = 0; k < 4; ++k) { s1[k] = s0[2*k] + s0[2*k+1]; tb1 += s0[2*k] - s0[2*k+1]; }
        #pragma unroll
        for (int k = 0; k < 2; ++k) { s2[k] = s1[2*k] + s1[2*k+1]; }
        tb2 = (s1[0] - s1[1]) + (s1[2] - s1[3]);
        S   = s2[0] + s2[1];
        tb3 = s2[0] - s2[1];

        // Walsh-Hadamard butterflies over the 6 lane bits: after the loop,
        // lane L holds sum_j (-1)^{popcount(L & j)} v_j for each sequence.
        float wS = S, w0t = tb0, w1t = tb1, w2t = tb2, w3t = tb3;
        #pragma unroll
        for (int m = 1; m < 64; m <<= 1) {
            float t;
            t = __shfl_xor(wS,  m, 64); wS  = (lane & m) ? (t - wS)  : (wS  + t);
            t = __shfl_xor(w0t, m, 64); w0t = (lane & m) ? (t - w0t) : (w0t + t);
            t = __shfl_xor(w1t, m, 64); w1t = (lane & m) ? (t - w1t) : (w1t + t);
            t = __shfl_xor(w2t, m, 64); w2t = (lane & m) ? (t - w2t) : (w2t + t);
            t = __shfl_xor(w3t, m, 64); w3t = (lane & m) ? (t - w3t) : (w3t + t);
        }
        float* ob = out + sample * NQ;
        if (lane == 16)      { ob[0] = wS; ob[5] = w3t; }   // masks: q0=16, q5=16
        else if (lane == 8)  { ob[1] = wS; ob[6] = w2t; }   // q1=8,  q6=8
        else if (lane == 4)  { ob[2] = wS; ob[7] = w1t; }   // q2=4,  q7=4
        else if (lane == 2)  { ob[3] = wS; ob[8] = w0t; }   // q3=2,  q8=2
        else if (lane == 1)  { ob[4] = wS; }                // q4=1
        else if (lane == 33) { ob[9] = wS; }                // q9 = lane0^lane5 -> 33
    }
}

extern "C" void kernel_launch(void* const* d_in, const int* in_sizes, int n_in,
                              void* d_out, int out_size, void* d_ws, size_t ws_size,
                              hipStream_t stream) {
    const float* x = (const float*)d_in[0];   // (16,256,20) fp32
    const float* w = (const float*)d_in[1];   // (4,10,3)   fp32
    float* out = (float*)d_out;               // (16,256,10) fp32
    const int n_samples = in_sizes[0] / (2 * NQ);  // 4096
    qsim_kernel<<<n_samples, 64, 0, stream>>>(x, w, out);
}